// Round 10
// baseline (205.200 us; speedup 1.0000x reference)
//
#include <hip/hip_runtime.h>
#include <hip/hip_bf16.h>
#include <hip/hip_cooperative_groups.h>

namespace cg = cooperative_groups;

#define LL 512
#define BB 32
#define DD 512
#define CINN 32
#define TOPK 6
#define BL (BB * LL)  // 16384

typedef __attribute__((ext_vector_type(8))) short bf16x8;
typedef __attribute__((ext_vector_type(4))) float f32x4;

__device__ inline float bf2f(ushort u) {
    union { uint i; float f; } c; c.i = ((uint)u) << 16; return c.f;
}
__device__ inline ushort f2bf(float f) {  // round-to-nearest-even
    union { float f; uint i; } c; c.f = f;
    uint i = c.i;
    return (ushort)((i + 0x7FFFu + ((i >> 16) & 1u)) >> 16);
}
__device__ inline void split_bf(float v, ushort& hi, ushort& lo) {
    hi = f2bf(v);
    lo = f2bf(v - bf2f(hi));
}
__device__ inline uint pk2(ushort a, ushort b) { return (uint)a | ((uint)b << 16); }

__device__ inline bf16x8 frag_ld(const ushort* sm, int r, int s) {
    return *(const bf16x8*)(sm + r * 32 + ((s ^ ((r >> 1) & 3)) << 3));
}

// One K=32 step of split-bf16 3-term MFMA (lo*lo dropped, ~2^-18).
__device__ inline void mfma_step(const ushort* sAh, const ushort* sAl,
                                 const ushort* sBh, const ushort* sBl,
                                 f32x4 acc[4][4], int wr, int wc, int fr, int fs) {
    bf16x8 bh[4], blo[4];
    #pragma unroll
    for (int ni = 0; ni < 4; ++ni) {
        bh[ni]  = frag_ld(sBh, wc + ni * 16 + fr, fs);
        blo[ni] = frag_ld(sBl, wc + ni * 16 + fr, fs);
    }
    #pragma unroll
    for (int mi = 0; mi < 4; ++mi) {
        const bf16x8 ah = frag_ld(sAh, wr + mi * 16 + fr, fs);
        const bf16x8 al = frag_ld(sAl, wr + mi * 16 + fr, fs);
        #pragma unroll
        for (int ni = 0; ni < 4; ++ni) {
            acc[mi][ni] = __builtin_amdgcn_mfma_f32_16x16x32_bf16(ah, bh[ni],  acc[mi][ni], 0, 0, 0);
            acc[mi][ni] = __builtin_amdgcn_mfma_f32_16x16x32_bf16(ah, blo[ni], acc[mi][ni], 0, 0, 0);
            acc[mi][ni] = __builtin_amdgcn_mfma_f32_16x16x32_bf16(al, bh[ni],  acc[mi][ni], 0, 0, 0);
        }
    }
}

// Single cooperative kernel: 512 blocks x 256 threads, 2 blocks/CU co-resident.
// P1: Mpart(64 blk)+upart(8) | P2: M-reduce(4)+v2part(8) | P3: corr(512) | P4: tail(32)
__global__ __launch_bounds__(256, 2) void uber(
    const float* __restrict__ x,
    const float* __restrict__ wq, const float* __restrict__ wk,
    const float* __restrict__ cw, const float* __restrict__ cb,
    const float* __restrict__ wv, const float* __restrict__ bv,
    const float* __restrict__ wo, const float* __restrict__ bo,
    const float* __restrict__ lin_w, const float* __restrict__ lin_b,
    float* __restrict__ Mpart, float* __restrict__ upart,
    float* __restrict__ Mfin, float* __restrict__ v2part,
    float* __restrict__ mcpart, float* __restrict__ out)
{
    __shared__ __align__(16) char smem[39424];   // union of all phase layouts
    cg::grid_group grid = cg::this_grid();
    const int bid = blockIdx.x, tid = threadIdx.x;

    // ---------------- P1: Mpart chunks + upart ----------------
    if (bid < 64) {
        float (*wqs)[512] = (float(*)[512])smem;            // 16 KB
        float (*wks)[512] = (float(*)[512])(smem + 16384);  // 16 KB
        float (*aqs)[32]  = (float(*)[32])(smem + 32768);
        float (*aks)[32]  = (float(*)[32])(smem + 33792);
        const int e0 = bid * 8;
        for (int i = tid; i < 4096; i += 256) {
            const int e = i >> 9, d = i & 511;   // consecutive tid -> consecutive d (coalesced)
            wqs[e][d] = wq[(long)(e0 + e) * 512 + d];
            wks[e][d] = wk[(long)(e0 + e) * 512 + d];
        }
        __syncthreads();
        const int e_loc = tid >> 5, c = tid & 31;
        float aq = 0.f, ak = 0.f;
        #pragma unroll 4
        for (int d = 0; d < 512; ++d) {          // cw row read coalesced across c-lanes (L1)
            const float cv = cw[(long)d * 32 + c];
            aq += wqs[e_loc][d] * cv;
            ak += wks[e_loc][d] * cv;
        }
        aqs[e_loc][c] = aq;
        aks[e_loc][c] = ak;
        __syncthreads();
        const int c_ = tid >> 3, cq = tid & 7;
        float m0 = 0.f, m1 = 0.f, m2 = 0.f, m3 = 0.f;
        #pragma unroll
        for (int e = 0; e < 8; ++e) {
            const float a = aqs[e][c_];
            const float4 k4 = *(const float4*)&aks[e][cq * 4];
            m0 += a * k4.x; m1 += a * k4.y; m2 += a * k4.z; m3 += a * k4.w;
        }
        *(float4*)(Mpart + (long)bid * 1024 + c_ * 32 + cq * 4) =
            make_float4(m0, m1, m2, m3);
    } else if (bid < 72) {
        const int j = bid - 64, n0 = j * 64;
        float u0 = 0.f, u1 = 0.f;
        for (int n = 0; n < 64; ++n) {
            const float lw = lin_w[n0 + n];
            u0 += lw * wo[(long)(n0 + n) * 512 + tid];
            u1 += lw * wo[(long)(n0 + n) * 512 + tid + 256];
        }
        upart[j * 512 + tid] = u0;
        upart[j * 512 + tid + 256] = u1;
    }
    grid.sync();

    // ---------------- P2: M-reduce (ascending p, deterministic) + v2part ----------------
    if (bid < 4) {
        const int entry = bid * 256 + tid;
        float s = 0.f;
        for (int p = 0; p < 64; ++p) s += Mpart[(long)p * 1024 + entry];
        Mfin[entry] = s;
    } else if (bid >= 8 && bid < 16) {
        const int j = bid - 8;
        float* us = (float*)smem;
        if (tid < 64) {
            float s = 0.f;
            #pragma unroll
            for (int i = 0; i < 8; ++i) s += upart[i * 512 + j * 64 + tid];
            us[tid] = s;
        }
        __syncthreads();
        float s0 = 0.f, s1 = 0.f;
        for (int dl = 0; dl < 64; ++dl) {
            const float ud = us[dl];
            s0 += ud * wv[(long)(j * 64 + dl) * 512 + tid];
            s1 += ud * wv[(long)(j * 64 + dl) * 512 + tid + 256];
        }
        v2part[j * 512 + tid] = s0;
        v2part[j * 512 + tid + 256] = s1;
    }
    grid.sync();

    // ---------------- P3: corr tile (all 512 blocks) ----------------
    {
        ushort* buf   = (ushort*)smem;                     // 32 KB: 4 regions x 128x32
        float (*Ml)[36] = (float(*)[36])(smem + 32768);    // 4.5 KB
        float* mcloc  = (float*)(smem + 32768 + 4608);     // 2 KB
        ushort* bufAh = buf;
        ushort* bufAl = buf + 4096;
        ushort* bufBh = buf + 8192;
        ushort* bufBl = buf + 12288;

        const int xcd = bid & 7, s = bid >> 3;
        const int b = xcd * 4 + (s >> 4);
        const int tile = s & 15;
        const int tm = tile >> 2, tn = tile & 3;

        {
            const float4 mv = *(const float4*)(Mfin + tid * 4);
            *(float4*)&Ml[tid >> 3][(tid & 7) * 4] = mv;
        }
        mcloc[tid] = 0.f; mcloc[tid + 256] = 0.f;

        // per-thread build: 2 physical 16B units of one row per region
        const int r = tid >> 1;               // 0..127
        const int pb = (tid & 1) * 2;         // phys slots {0,1} or {2,3}
        const int swz = (r >> 1) & 3;
        const float* xA = x + ((long)b * LL + tm * 128 + r) * 32;
        const float* xB = x + ((long)b * LL + tn * 128 + r) * 32;
        float xb[32];
        #pragma unroll
        for (int q = 0; q < 8; ++q)
            *(float4*)&xb[q * 4] = *(const float4*)(xB + q * 4);

        __syncthreads();   // Ml + mcloc ready

        #pragma unroll
        for (int pi = 0; pi < 2; ++pi) {
            const int p = pb + pi;
            const int sl = p ^ swz;           // logical 8-col slot
            const int uoff = (r * 4 + p) * 8; // linear ushort offset in region
            const float4 a0 = *(const float4*)(xA + sl * 8);
            const float4 a1 = *(const float4*)(xA + sl * 8 + 4);
            const float xe[8] = {a0.x, a0.y, a0.z, a0.w, a1.x, a1.y, a1.z, a1.w};
            ushort xh[8], xl[8];
            #pragma unroll
            for (int j = 0; j < 8; ++j) split_bf(xe[j], xh[j], xl[j]);
            *(uint4*)(bufAh + uoff) = make_uint4(pk2(xh[0], xh[1]), pk2(xh[2], xh[3]),
                                                 pk2(xh[4], xh[5]), pk2(xh[6], xh[7]));
            *(uint4*)(bufAl + uoff) = make_uint4(pk2(xl[0], xl[1]), pk2(xl[2], xl[3]),
                                                 pk2(xl[4], xl[5]), pk2(xl[6], xl[7]));
            // U slot: u[c] = sum_d M[c][d] x[d] (q-ascending, bit-stable order)
            float uv[8];
            #pragma unroll
            for (int j = 0; j < 8; ++j) {
                const int c = sl * 8 + j;
                float sacc = 0.f;
                #pragma unroll
                for (int q = 0; q < 8; ++q) {
                    const float4 m = *(const float4*)&Ml[c][q * 4];
                    sacc += m.x * xb[q * 4] + m.y * xb[q * 4 + 1]
                          + m.z * xb[q * 4 + 2] + m.w * xb[q * 4 + 3];
                }
                uv[j] = sacc;
            }
            ushort uh[8], ul[8];
            #pragma unroll
            for (int j = 0; j < 8; ++j) split_bf(uv[j], uh[j], ul[j]);
            *(uint4*)(bufBh + uoff) = make_uint4(pk2(uh[0], uh[1]), pk2(uh[2], uh[3]),
                                                 pk2(uh[4], uh[5]), pk2(uh[6], uh[7]));
            *(uint4*)(bufBl + uoff) = make_uint4(pk2(ul[0], ul[1]), pk2(ul[2], ul[3]),
                                                 pk2(ul[4], ul[5]), pk2(ul[6], ul[7]));
        }
        __syncthreads();   // tiles built

        const int wid = tid >> 6, lane = tid & 63;
        const int wr = (wid >> 1) * 64, wc = (wid & 1) * 64;
        const int fr = lane & 15, fs = lane >> 4;
        f32x4 acc[4][4] = {};
        mfma_step(bufAh, bufAl, bufBh, bufBl, acc, wr, wc, fr, fs);

        // pre-sum same-diagonal accs: diag = 16k + base, k = mi-ni
        const int base = wr - wc + 128 * (tm - tn) + fs * 4 - fr;
        #pragma unroll
        for (int k = -3; k <= 3; ++k) {
            #pragma unroll
            for (int rr = 0; rr < 4; ++rr) {
                float sdg = 0.f;
                #pragma unroll
                for (int mi = 0; mi < 4; ++mi) {
                    const int ni = mi - k;
                    if (ni >= 0 && ni < 4) sdg += acc[mi][ni][rr];
                }
                atomicAdd(&mcloc[(base + 16 * k + rr) & (LL - 1)], sdg);
            }
        }
        __syncthreads();
        float* o = mcpart + ((long)b * 16 + tile) * LL;
        o[tid] = mcloc[tid];
        o[tid + 256] = mcloc[tid + 256];
    }
    grid.sync();

    // ---------------- P4: tail (32 blocks) ----------------
    if (bid < 32) {
        float* fb   = (float*)smem;
        float* v2s  = fb;            // 512
        float* us2  = fb + 512;      // 512
        float (*w3p)[32] = (float(*)[32])(fb + 1024);  // 8x32
        float (*w4p)[32] = (float(*)[32])(fb + 1280);  // 8x32
        float* w3s  = fb + 1536;     // 32
        float* w4s  = fb + 1568;     // 32
        float* swv  = fb + 1600;     // 4
        float* selv = fb + 1604;     // 6
        float* wts  = fb + 1610;     // 6
        float* redc = fb + 1616;     // 4
        float* c2s  = fb + 1620;     // 1
        int*   swi  = (int*)(fb + 1624);  // 4
        int*   seli = (int*)(fb + 1628);  // 6

        const int b = bid;
        const int lane = tid & 63, wid = tid >> 6;

        {
            float a0 = 0.f, a1 = 0.f, b0 = 0.f, b1 = 0.f;
            #pragma unroll
            for (int i = 0; i < 8; ++i) {
                a0 += v2part[i * 512 + tid];
                a1 += v2part[i * 512 + tid + 256];
                b0 += upart[i * 512 + tid];
                b1 += upart[i * 512 + tid + 256];
            }
            v2s[tid] = a0; v2s[tid + 256] = a1;
            us2[tid] = b0; us2[tid + 256] = b1;
        }
        __syncthreads();
        {
            const int c = tid & 31, g = tid >> 5;
            float w3 = 0.f, w4 = 0.f;
            for (int dl = 0; dl < 64; ++dl) {
                const int d = g * 64 + dl;
                const float cwv = cw[(long)d * 32 + c];
                w3 += v2s[d] * cwv;
                w4 += lin_w[d] * cwv;
            }
            w3p[g][c] = w3; w4p[g][c] = w4;
        }
        __syncthreads();
        if (tid < 32) {
            float a3 = 0.f, a4 = 0.f;
            #pragma unroll
            for (int g2 = 0; g2 < 8; ++g2) { a3 += w3p[g2][tid]; a4 += w4p[g2][tid]; }
            w3s[tid] = a3; w4s[tid] = a4;
        }
        {
            float p = cb[tid] * (v2s[tid] + lin_w[tid])
                    + cb[tid + 256] * (v2s[tid + 256] + lin_w[tid + 256])
                    + bv[tid] * us2[tid] + bv[tid + 256] * us2[tid + 256]
                    + bo[tid] * lin_w[tid] + bo[tid + 256] * lin_w[tid + 256];
            #pragma unroll
            for (int o = 32; o; o >>= 1) p += __shfl_down(p, o);
            if ((tid & 63) == 0) redc[tid >> 6] = p;
        }
        __syncthreads();
        if (tid == 0) c2s[0] = redc[0] + redc[1] + redc[2] + redc[3] + lin_b[0];

        // mc reduce
        float v0 = 0.f, v1 = 0.f;
        #pragma unroll
        for (int j = 0; j < 16; ++j) {
            v0 += mcpart[((long)b * 16 + j) * LL + tid];
            v1 += mcpart[((long)b * 16 + j) * LL + tid + 256];
        }
        v0 *= (1.0f / DD); v1 *= (1.0f / DD);

        // top-6 via wave shuffle (max value, min index on ties)
        int live0 = 1, live1 = 1;
        for (int r = 0; r < TOPK; ++r) {
            float bvv = -1e30f; int bi = -1;
            if (live0) { bvv = v0; bi = tid; }
            if (live1 && v1 > bvv) { bvv = v1; bi = tid + 256; }
            #pragma unroll
            for (int o = 32; o; o >>= 1) {
                const float ov = __shfl_down(bvv, o);
                const int oi = __shfl_down(bi, o);
                if (ov > bvv || (ov == bvv && oi < bi)) { bvv = ov; bi = oi; }
            }
            if (lane == 0) { swv[wid] = bvv; swi[wid] = bi; }
            __syncthreads();
            if (tid == 0) {
                float fv = swv[0]; int fi = swi[0];
                #pragma unroll
                for (int w2 = 1; w2 < 4; ++w2) {
                    if (swv[w2] > fv || (swv[w2] == fv && swi[w2] < fi)) { fv = swv[w2]; fi = swi[w2]; }
                }
                selv[r] = fv; seli[r] = fi;
            }
            __syncthreads();
            const int w = seli[r];
            if (w == tid)       live0 = 0;
            if (w == tid + 256) live1 = 0;
        }
        if (tid == 0) {
            const float mx = selv[0];
            float e[TOPK], ssum = 0.f;
            #pragma unroll
            for (int k = 0; k < TOPK; ++k) { e[k] = expf(selv[k] - mx); ssum += e[k]; }
            #pragma unroll
            for (int k = 0; k < TOPK; ++k) wts[k] = e[k] / ssum;
        }
        __syncthreads();

        // y = <xlast, w4> + <xmix, w3> + c2
        if (tid < CINN) {
            float xm = 0.f;
            #pragma unroll
            for (int k = 0; k < TOPK; ++k) {
                const int r = (LL - 1 + seli[k]) & (LL - 1);
                xm += wts[k] * x[((long)b * LL + r) * CINN + tid];
            }
            const float xlv = x[((long)b * LL + (LL - 1)) * CINN + tid];
            float yv = xlv * w4s[tid] + xm * w3s[tid];
            #pragma unroll
            for (int o = 16; o; o >>= 1) yv += __shfl_down(yv, o);
            if (tid == 0) out[b] = yv + c2s[0];
        }
    }
}

extern "C" void kernel_launch(void* const* d_in, const int* in_sizes, int n_in,
                              void* d_out, int out_size, void* d_ws, size_t ws_size,
                              hipStream_t stream) {
    const float* x      = (const float*)d_in[0];
    const float* conv_w = (const float*)d_in[1];
    const float* conv_b = (const float*)d_in[2];
    const float* wq     = (const float*)d_in[3];
    const float* wk     = (const float*)d_in[5];
    const float* wv     = (const float*)d_in[7];
    const float* bv     = (const float*)d_in[8];
    const float* wo     = (const float*)d_in[9];
    const float* bo     = (const float*)d_in[10];
    const float* lin_w  = (const float*)d_in[11];
    const float* lin_b  = (const float*)d_in[12];
    // bq, bk and all bias terms inside mean_corr are tau-constant -> dropped
    // (softmax/top-k shift-invariant).

    char* w = (char*)d_ws;
    float* Mpart  = (float*)w;  w += (long)64 * 1024 * 4;      // 256 KB
    float* upart  = (float*)w;  w += (long)8 * 512 * 4;        // 16 KB
    float* Mfin   = (float*)w;  w += (long)1024 * 4;           // 4 KB
    float* v2part = (float*)w;  w += (long)8 * 512 * 4;        // 16 KB
    float* mcpart = (float*)w;  w += (long)BB * 16 * LL * 4;   // 1 MB
    float* yout   = (float*)d_out;

    void* args[] = {
        (void*)&x, (void*)&wq, (void*)&wk, (void*)&conv_w, (void*)&conv_b,
        (void*)&wv, (void*)&bv, (void*)&wo, (void*)&bo,
        (void*)&lin_w, (void*)&lin_b,
        (void*)&Mpart, (void*)&upart, (void*)&Mfin, (void*)&v2part,
        (void*)&mcpart, (void*)&yout
    };
    hipLaunchCooperativeKernel((const void*)uber, dim3(512), dim3(256),
                               args, 0, stream);
}

// Round 11
// 61.077 us; speedup vs baseline: 3.3597x; 3.3597x over previous
//
#include <hip/hip_runtime.h>
#include <hip/hip_bf16.h>

#define LL 512
#define BB 32
#define DD 512
#define CINN 32
#define TOPK 6
#define BL (BB * LL)  // 16384

typedef __attribute__((ext_vector_type(8))) short bf16x8;
typedef __attribute__((ext_vector_type(4))) float f32x4;

__device__ inline float bf2f(ushort u) {
    union { uint i; float f; } c; c.i = ((uint)u) << 16; return c.f;
}
__device__ inline ushort f2bf(float f) {  // round-to-nearest-even
    union { float f; uint i; } c; c.f = f;
    uint i = c.i;
    return (ushort)((i + 0x7FFFu + ((i >> 16) & 1u)) >> 16);
}
__device__ inline void split_bf(float v, ushort& hi, ushort& lo) {
    hi = f2bf(v);
    lo = f2bf(v - bf2f(hi));
}
__device__ inline uint pk2(ushort a, ushort b) { return (uint)a | ((uint)b << 16); }

__device__ inline bf16x8 frag_ld(const ushort* sm, int r, int s) {
    return *(const bf16x8*)(sm + r * 32 + ((s ^ ((r >> 1) & 3)) << 3));
}

// One K=32 step of split-bf16 3-term MFMA (lo*lo dropped, ~2^-18).
__device__ inline void mfma_step(const ushort* sAh, const ushort* sAl,
                                 const ushort* sBh, const ushort* sBl,
                                 f32x4 acc[4][4], int wr, int wc, int fr, int fs) {
    bf16x8 bh[4], blo[4];
    #pragma unroll
    for (int ni = 0; ni < 4; ++ni) {
        bh[ni]  = frag_ld(sBh, wc + ni * 16 + fr, fs);
        blo[ni] = frag_ld(sBl, wc + ni * 16 + fr, fs);
    }
    #pragma unroll
    for (int mi = 0; mi < 4; ++mi) {
        const bf16x8 ah = frag_ld(sAh, wr + mi * 16 + fr, fs);
        const bf16x8 al = frag_ld(sAl, wr + mi * 16 + fr, fs);
        #pragma unroll
        for (int ni = 0; ni < 4; ++ni) {
            acc[mi][ni] = __builtin_amdgcn_mfma_f32_16x16x32_bf16(ah, bh[ni],  acc[mi][ni], 0, 0, 0);
            acc[mi][ni] = __builtin_amdgcn_mfma_f32_16x16x32_bf16(ah, blo[ni], acc[mi][ni], 0, 0, 0);
            acc[mi][ni] = __builtin_amdgcn_mfma_f32_16x16x32_bf16(al, bh[ni],  acc[mi][ni], 0, 0, 0);
        }
    }
}

// ---- K1: blocks 0..63:  e-chunk i (8 rows of wq,wk):
//            Aqc = wq_chunk@cw, Akc = wk_chunk@cw  ->  Mpart[i] = Aqc^T Akc.
//          blocks 64..71: upart[j][d] = sum_{n in 64-chunk} lin_w[n] wo[n][d].
__global__ __launch_bounds__(256) void prep_m(
    const float* __restrict__ wq, const float* __restrict__ wk,
    const float* __restrict__ cw,
    const float* __restrict__ lin_w, const float* __restrict__ wo,
    float* __restrict__ Mpart, float* __restrict__ upart)
{
    const int tid = threadIdx.x;
    if (blockIdx.x < 64) {
        __shared__ float cws[512][32];     // read: same d, c=bank -> conflict-free
        __shared__ float wqsT[512][9];     // stride 9: staging & reads conflict-free
        __shared__ float wksT[512][9];
        __shared__ float aqs[8][32];
        __shared__ float aks[8][32];
        for (int i = tid; i < 4096; i += 256) {
            const int d = i >> 3, q = i & 7;
            *(float4*)&cws[d][q * 4] = *(const float4*)(cw + (long)d * 32 + q * 4);
        }
        const int e0 = blockIdx.x * 8;
        for (int i = tid; i < 4096; i += 256) {
            const int e = i >> 9, d = i & 511;
            wqsT[d][e] = wq[(long)(e0 + e) * 512 + d];
            wksT[d][e] = wk[(long)(e0 + e) * 512 + d];
        }
        __syncthreads();
        const int e_loc = tid >> 5, c = tid & 31;
        float aq = 0.f, ak = 0.f;
        #pragma unroll 4
        for (int d = 0; d < 512; ++d) {
            const float cv = cws[d][c];
            aq += wqsT[d][e_loc] * cv;
            ak += wksT[d][e_loc] * cv;
        }
        aqs[e_loc][c] = aq;
        aks[e_loc][c] = ak;
        __syncthreads();
        const int c_ = tid >> 3, cq = tid & 7;
        float m0 = 0.f, m1 = 0.f, m2 = 0.f, m3 = 0.f;
        #pragma unroll
        for (int e = 0; e < 8; ++e) {
            const float a = aqs[e][c_];
            const float4 k4 = *(const float4*)&aks[e][cq * 4];
            m0 += a * k4.x; m1 += a * k4.y; m2 += a * k4.z; m3 += a * k4.w;
        }
        *(float4*)(Mpart + (long)blockIdx.x * 1024 + c_ * 32 + cq * 4) =
            make_float4(m0, m1, m2, m3);
    } else {
        const int j = blockIdx.x - 64;
        const int n0 = j * 64;
        float u0 = 0.f, u1 = 0.f;
        for (int n = 0; n < 64; ++n) {
            const float lw = lin_w[n0 + n];
            u0 += lw * wo[(long)(n0 + n) * 512 + tid];
            u1 += lw * wo[(long)(n0 + n) * 512 + tid + 256];
        }
        upart[j * 512 + tid] = u0;
        upart[j * 512 + tid + 256] = u1;
    }
}

// ---- K2 (12 blocks): 0..3: Mfin = sum_p Mpart (ascending p, deterministic,
//            bit-identical to R9's per-block reduce). 4..11: v2part.
__global__ __launch_bounds__(256) void prep_s(
    const float* __restrict__ Mpart, const float* __restrict__ upart,
    const float* __restrict__ wv,
    float* __restrict__ Mfin, float* __restrict__ v2part)
{
    const int tid = threadIdx.x;
    if (blockIdx.x < 4) {
        const int entry = blockIdx.x * 256 + tid;
        float s = 0.f;
        for (int p = 0; p < 64; ++p) s += Mpart[(long)p * 1024 + entry];
        Mfin[entry] = s;
    } else {
        const int j = blockIdx.x - 4;
        __shared__ float us[64];
        if (tid < 64) {
            float s = 0.f;
            #pragma unroll
            for (int i = 0; i < 8; ++i) s += upart[i * 512 + j * 64 + tid];
            us[tid] = s;
        }
        __syncthreads();
        float s0 = 0.f, s1 = 0.f;
        for (int dl = 0; dl < 64; ++dl) {
            const float ud = us[dl];
            s0 += ud * wv[(long)(j * 64 + dl) * 512 + tid];
            s1 += ud * wv[(long)(j * 64 + dl) * 512 + tid + 256];
        }
        v2part[j * 512 + tid] = s0;
        v2part[j * 512 + tid + 256] = s1;
    }
}

// ---- K3 (512 blocks): per (batch, 128x128 tile): load M (4KB), build
//      X-split and U = M x tiles in LDS (linear ds_write, inverse-involution
//      mapping); one K=32 3-term MFMA step; wrapped-diag reduce -> mcpart.
__global__ __launch_bounds__(256, 2) void corr_kernel(
    const float* __restrict__ x, const float* __restrict__ Mfin,
    float* __restrict__ mcpart)
{
    __shared__ ushort buf[16384];   // 4 regions x (128 rows x 4 units x 8 ush)
    __shared__ float Ml[32][36];
    __shared__ float mcloc[LL];
    ushort* bufAh = buf;
    ushort* bufAl = buf + 4096;
    ushort* bufBh = buf + 8192;
    ushort* bufBl = buf + 12288;
    const int tid = threadIdx.x;

    const int xcd = blockIdx.x & 7, s = blockIdx.x >> 3;
    const int b = xcd * 4 + (s >> 4);
    const int tile = s & 15;
    const int tm = tile >> 2, tn = tile & 3;

    {
        const float4 mv = *(const float4*)(Mfin + tid * 4);
        *(float4*)&Ml[tid >> 3][(tid & 7) * 4] = mv;
    }
    mcloc[tid] = 0.f; mcloc[tid + 256] = 0.f;

    // per-thread build: 2 physical 16B units of one row per region
    const int r = tid >> 1;               // 0..127
    const int pb = (tid & 1) * 2;         // phys slots {0,1} or {2,3}
    const int swz = (r >> 1) & 3;
    const float* xA = x + ((long)b * LL + tm * 128 + r) * 32;
    const float* xB = x + ((long)b * LL + tn * 128 + r) * 32;
    float xb[32];
    #pragma unroll
    for (int q = 0; q < 8; ++q)
        *(float4*)&xb[q * 4] = *(const float4*)(xB + q * 4);

    __syncthreads();   // Ml + mcloc ready

    #pragma unroll
    for (int pi = 0; pi < 2; ++pi) {
        const int p = pb + pi;
        const int sl = p ^ swz;           // logical 8-col slot
        const int uoff = (r * 4 + p) * 8; // linear ushort offset in region
        const float4 a0 = *(const float4*)(xA + sl * 8);
        const float4 a1 = *(const float4*)(xA + sl * 8 + 4);
        const float xe[8] = {a0.x, a0.y, a0.z, a0.w, a1.x, a1.y, a1.z, a1.w};
        ushort xh[8], xl[8];
        #pragma unroll
        for (int j = 0; j < 8; ++j) split_bf(xe[j], xh[j], xl[j]);
        *(uint4*)(bufAh + uoff) = make_uint4(pk2(xh[0], xh[1]), pk2(xh[2], xh[3]),
                                             pk2(xh[4], xh[5]), pk2(xh[6], xh[7]));
        *(uint4*)(bufAl + uoff) = make_uint4(pk2(xl[0], xl[1]), pk2(xl[2], xl[3]),
                                             pk2(xl[4], xl[5]), pk2(xl[6], xl[7]));
        // U slot: u[c] = sum_d M[c][d] x[d] (q-ascending, bit-stable order)
        float uv[8];
        #pragma unroll
        for (int j = 0; j < 8; ++j) {
            const int c = sl * 8 + j;
            float sacc = 0.f;
            #pragma unroll
            for (int q = 0; q < 8; ++q) {
                const float4 m = *(const float4*)&Ml[c][q * 4];
                sacc += m.x * xb[q * 4] + m.y * xb[q * 4 + 1]
                      + m.z * xb[q * 4 + 2] + m.w * xb[q * 4 + 3];
            }
            uv[j] = sacc;
        }
        ushort uh[8], ul[8];
        #pragma unroll
        for (int j = 0; j < 8; ++j) split_bf(uv[j], uh[j], ul[j]);
        *(uint4*)(bufBh + uoff) = make_uint4(pk2(uh[0], uh[1]), pk2(uh[2], uh[3]),
                                             pk2(uh[4], uh[5]), pk2(uh[6], uh[7]));
        *(uint4*)(bufBl + uoff) = make_uint4(pk2(ul[0], ul[1]), pk2(ul[2], ul[3]),
                                             pk2(ul[4], ul[5]), pk2(ul[6], ul[7]));
    }
    __syncthreads();   // tiles built

    const int wid = tid >> 6, lane = tid & 63;
    const int wr = (wid >> 1) * 64, wc = (wid & 1) * 64;
    const int fr = lane & 15, fs = lane >> 4;
    f32x4 acc[4][4] = {};
    mfma_step(bufAh, bufAl, bufBh, bufBl, acc, wr, wc, fr, fs);

    // pre-sum same-diagonal accs: diag = 16k + base, k = mi-ni
    const int base = wr - wc + 128 * (tm - tn) + fs * 4 - fr;
    #pragma unroll
    for (int k = -3; k <= 3; ++k) {
        #pragma unroll
        for (int rr = 0; rr < 4; ++rr) {
            float sdg = 0.f;
            #pragma unroll
            for (int mi = 0; mi < 4; ++mi) {
                const int ni = mi - k;
                if (ni >= 0 && ni < 4) sdg += acc[mi][ni][rr];
            }
            atomicAdd(&mcloc[(base + 16 * k + rr) & (LL - 1)], sdg);
        }
    }
    __syncthreads();
    float* o = mcpart + ((long)b * 16 + tile) * LL;
    o[tid] = mcloc[tid];
    o[tid + 256] = mcloc[tid + 256];
}

// ---- K4: per batch: mc-reduce + top-6 (wave-shuffle) + softmax +
//          local w3/w4/c2 (redundant, trivial) + y.
__global__ __launch_bounds__(256) void tail_kernel(
    const float* __restrict__ mcpart, const float* __restrict__ x,
    const float* __restrict__ upart, const float* __restrict__ v2part,
    const float* __restrict__ cw, const float* __restrict__ cb,
    const float* __restrict__ lin_w, const float* __restrict__ bv,
    const float* __restrict__ bo, const float* __restrict__ lin_b,
    float* __restrict__ out)
{
    const int b = blockIdx.x, tid = threadIdx.x;
    const int lane = tid & 63, wid = tid >> 6;
    __shared__ float v2s[512];
    __shared__ float us2[512];
    __shared__ float w3p[8][32];
    __shared__ float w4p[8][32];
    __shared__ float w3s[32];
    __shared__ float w4s[32];
    __shared__ float c2s;
    __shared__ float swv[4];
    __shared__ int   swi[4];
    __shared__ float selv[TOPK];
    __shared__ int   seli[TOPK];
    __shared__ float wts[TOPK];
    __shared__ float redc[4];

    {
        float a0 = 0.f, a1 = 0.f, b0 = 0.f, b1 = 0.f;
        #pragma unroll
        for (int i = 0; i < 8; ++i) {
            a0 += v2part[i * 512 + tid];
            a1 += v2part[i * 512 + tid + 256];
            b0 += upart[i * 512 + tid];
            b1 += upart[i * 512 + tid + 256];
        }
        v2s[tid] = a0; v2s[tid + 256] = a1;
        us2[tid] = b0; us2[tid + 256] = b1;
    }
    __syncthreads();
    {
        const int c = tid & 31, g = tid >> 5;
        float w3 = 0.f, w4 = 0.f;
        for (int dl = 0; dl < 64; ++dl) {
            const int d = g * 64 + dl;
            const float cwv = cw[(long)d * 32 + c];
            w3 += v2s[d] * cwv;
            w4 += lin_w[d] * cwv;
        }
        w3p[g][c] = w3; w4p[g][c] = w4;
    }
    __syncthreads();
    if (tid < 32) {
        float a3 = 0.f, a4 = 0.f;
        #pragma unroll
        for (int g2 = 0; g2 < 8; ++g2) { a3 += w3p[g2][tid]; a4 += w4p[g2][tid]; }
        w3s[tid] = a3; w4s[tid] = a4;
    }
    {
        float p = cb[tid] * (v2s[tid] + lin_w[tid])
                + cb[tid + 256] * (v2s[tid + 256] + lin_w[tid + 256])
                + bv[tid] * us2[tid] + bv[tid + 256] * us2[tid + 256]
                + bo[tid] * lin_w[tid] + bo[tid + 256] * lin_w[tid + 256];
        #pragma unroll
        for (int o = 32; o; o >>= 1) p += __shfl_down(p, o);
        if ((tid & 63) == 0) redc[tid >> 6] = p;
    }
    __syncthreads();
    if (tid == 0) c2s = redc[0] + redc[1] + redc[2] + redc[3] + lin_b[0];

    // mc reduce
    float v0 = 0.f, v1 = 0.f;
    #pragma unroll
    for (int j = 0; j < 16; ++j) {
        v0 += mcpart[((long)b * 16 + j) * LL + tid];
        v1 += mcpart[((long)b * 16 + j) * LL + tid + 256];
    }
    v0 *= (1.0f / DD); v1 *= (1.0f / DD);

    // top-6 via wave shuffle (max value, min index on ties)
    int live0 = 1, live1 = 1;
    for (int r = 0; r < TOPK; ++r) {
        float bvv = -1e30f; int bi = -1;
        if (live0) { bvv = v0; bi = tid; }
        if (live1 && v1 > bvv) { bvv = v1; bi = tid + 256; }
        #pragma unroll
        for (int o = 32; o; o >>= 1) {
            const float ov = __shfl_down(bvv, o);
            const int oi = __shfl_down(bi, o);
            if (ov > bvv || (ov == bvv && oi < bi)) { bvv = ov; bi = oi; }
        }
        if (lane == 0) { swv[wid] = bvv; swi[wid] = bi; }
        __syncthreads();
        if (tid == 0) {
            float fv = swv[0]; int fi = swi[0];
            #pragma unroll
            for (int w2 = 1; w2 < 4; ++w2) {
                if (swv[w2] > fv || (swv[w2] == fv && swi[w2] < fi)) { fv = swv[w2]; fi = swi[w2]; }
            }
            selv[r] = fv; seli[r] = fi;
        }
        __syncthreads();
        const int w = seli[r];
        if (w == tid)       live0 = 0;
        if (w == tid + 256) live1 = 0;
    }
    if (tid == 0) {
        const float mx = selv[0];
        float e[TOPK], ssum = 0.f;
        #pragma unroll
        for (int k = 0; k < TOPK; ++k) { e[k] = expf(selv[k] - mx); ssum += e[k]; }
        #pragma unroll
        for (int k = 0; k < TOPK; ++k) wts[k] = e[k] / ssum;
    }
    __syncthreads();

    // y = <xlast, w4> + <xmix, w3> + c2
    if (tid < CINN) {
        float xm = 0.f;
        #pragma unroll
        for (int k = 0; k < TOPK; ++k) {
            const int r = (LL - 1 + seli[k]) & (LL - 1);
            xm += wts[k] * x[((long)b * LL + r) * CINN + tid];
        }
        const float xlv = x[((long)b * LL + (LL - 1)) * CINN + tid];
        float yv = xlv * w4s[tid] + xm * w3s[tid];
        #pragma unroll
        for (int o = 16; o; o >>= 1) yv += __shfl_down(yv, o);
        if (tid == 0) out[b] = yv + c2s;
    }
}

extern "C" void kernel_launch(void* const* d_in, const int* in_sizes, int n_in,
                              void* d_out, int out_size, void* d_ws, size_t ws_size,
                              hipStream_t stream) {
    const float* x      = (const float*)d_in[0];
    const float* conv_w = (const float*)d_in[1];
    const float* conv_b = (const float*)d_in[2];
    const float* wq     = (const float*)d_in[3];
    const float* wk     = (const float*)d_in[5];
    const float* wv     = (const float*)d_in[7];
    const float* bv     = (const float*)d_in[8];
    const float* wo     = (const float*)d_in[9];
    const float* bo     = (const float*)d_in[10];
    const float* lin_w  = (const float*)d_in[11];
    const float* lin_b  = (const float*)d_in[12];
    // bq, bk and all bias terms inside mean_corr are tau-constant -> dropped
    // (softmax/top-k shift-invariant).

    char* w = (char*)d_ws;
    float* Mpart  = (float*)w;  w += (long)64 * 1024 * 4;      // 256 KB
    float* upart  = (float*)w;  w += (long)8 * 512 * 4;        // 16 KB
    float* Mfin   = (float*)w;  w += (long)1024 * 4;           // 4 KB
    float* v2part = (float*)w;  w += (long)8 * 512 * 4;        // 16 KB
    float* mcpart = (float*)w;  w += (long)BB * 16 * LL * 4;   // 1 MB
    float* yout   = (float*)d_out;

    // Mpart (0..63) | upart (64..71)
    prep_m<<<72, 256, 0, stream>>>(wq, wk, conv_w, lin_w, wo, Mpart, upart);
    // Mfin (0..3, ascending-p deterministic) | v2part (4..11)
    prep_s<<<12, 256, 0, stream>>>(Mpart, upart, wv, Mfin, v2part);
    // corr tiles: M load (4KB) + X/U build + MFMA + wrapped-diag
    corr_kernel<<<512, 256, 0, stream>>>(x, Mfin, mcpart);
    // mc reduce + top-6 + softmax + local w3/w4/c2 + y
    tail_kernel<<<BB, 256, 0, stream>>>(mcpart, x, upart, v2part,
                                        conv_w, conv_b, lin_w, bv, bo, lin_b, yout);
}